// Round 16
// baseline (68.513 us; speedup 1.0000x reference)
//
#include <hip/hip_runtime.h>
#include <hip/hip_bf16.h>

// DenseGridNet R16: EXACTLY R13 (fused, transposed in-register MLP, row-paired
// bf16 table, launch_bounds(256,3), depth-2 pipeline) with ONE change:
// grid cap 768 -> 1536 (6 blocks/CU at runtime: VGPR 72*6waves=432<=512/SIMD,
// LDS 19.25KB*6=115.5<=160KB). Tests wave-count as the concurrency lever.

typedef __attribute__((ext_vector_type(8))) short bf16x8;
typedef __attribute__((ext_vector_type(4))) float f32x4;
typedef __attribute__((ext_vector_type(2))) unsigned int u32x2;
typedef __attribute__((ext_vector_type(4))) unsigned int u32x4;
typedef unsigned long long u64t;

#define HID 64

static __device__ __forceinline__ unsigned short f2bf(float f) {
    __hip_bfloat16 h = __float2bfloat16(f);
    return __builtin_bit_cast(unsigned short, h);
}
static __device__ __forceinline__ unsigned cvt_pk_bf16(float a, float b) {
    unsigned r;
    asm("v_cvt_pk_bf16_f32 %0, %1, %2" : "=v"(r) : "v"(a), "v"(b));
    return r;
}
static __device__ __forceinline__ void lds_fence() {
    asm volatile("s_waitcnt lgkmcnt(0)" ::: "memory");
}
#define MFMA16(a,b,c) __builtin_amdgcn_mfma_f32_16x16x32_bf16((a),(b),(c),0,0,0)

// unpack 4 bf16 (2 packed u32) -> f32x4
static __device__ __forceinline__ f32x4 unpk2(unsigned lo, unsigned hi) {
    f32x4 r;
    r[0] = __builtin_bit_cast(float, lo << 16);
    r[1] = __builtin_bit_cast(float, lo & 0xFFFF0000u);
    r[2] = __builtin_bit_cast(float, hi << 16);
    r[3] = __builtin_bit_cast(float, hi & 0xFFFF0000u);
    return r;
}
// relu + pack two f32x4 accs into one B-frag (k-order: lo[0..3], hi[0..3])
static __device__ __forceinline__ bf16x8 pack_pair(f32x4 lo, f32x4 hi) {
    u32x4 w;
    w[0] = cvt_pk_bf16(fmaxf(lo[0], 0.f), fmaxf(lo[1], 0.f));
    w[1] = cvt_pk_bf16(fmaxf(lo[2], 0.f), fmaxf(lo[3], 0.f));
    w[2] = cvt_pk_bf16(fmaxf(hi[0], 0.f), fmaxf(hi[1], 0.f));
    w[3] = cvt_pk_bf16(fmaxf(hi[2], 0.f), fmaxf(hi[3], 0.f));
    return __builtin_bit_cast(bf16x8, w);
}

// ---- weight A-fragments for the transposed scheme ----
struct TFrags {
    bf16x8 a1[4];        // W1^T rows mt*16+cl, k=0..5 (idf,g0..3,bias-row)
    bf16x8 a2[4][2];     // W2^T, K in kappa order
    bf16x8 a3[2];        // W3^T (rows 0..2 valid), kappa order
    f32x4  bias2[4];
    f32x4  bias3;
};

// Wst layout (floats): [0..4095]=w2, [4096..4415]=w1, [4416..4479]=b1,
//                      [4480..4671]=w3, [4672..4735]=b2, [4736..4738]=b3
static __device__ __forceinline__ void build_tfrags(
    float* Wst, int tid, int cl, int kg,
    const float* __restrict__ w1, const float* __restrict__ b1,
    const float* __restrict__ w2, const float* __restrict__ b2,
    const float* __restrict__ w3, const float* __restrict__ b3, TFrags& F)
{
    {
        const f32x4* w2v = (const f32x4*)w2;
        f32x4* Wv = (f32x4*)Wst;
        #pragma unroll
        for (int i = 0; i < 4; ++i) Wv[tid + 256 * i] = w2v[tid + 256 * i];
        for (int idx = tid; idx < 320; idx += 256) Wst[4096 + idx] = w1[idx];
        if (tid < 64)  Wst[4416 + tid] = b1[tid];
        if (tid < 192) Wst[4480 + tid] = w3[tid];
        if (tid < 64)  Wst[4672 + tid] = b2[tid];
        if (tid < 3)   Wst[4736 + tid] = b3[tid];
    }
    __syncthreads();

    #pragma unroll
    for (int mt = 0; mt < 4; ++mt) {
        bf16x8 f = {};
        if (kg == 0) {
            int hid = mt * 16 + cl;
            #pragma unroll
            for (int j = 0; j < 5; ++j) f[j] = (short)f2bf(Wst[4096 + j * 64 + hid]);
            f[5] = (short)f2bf(Wst[4416 + hid]);   // bias row (input slot5 = 1.0)
        }
        F.a1[mt] = f;
    }
    #pragma unroll
    for (int ks = 0; ks < 2; ++ks) {
        #pragma unroll
        for (int mt2 = 0; mt2 < 4; ++mt2) {
            bf16x8 f;
            #pragma unroll
            for (int j = 0; j < 8; ++j) {
                int kap = (2 * ks + (j >> 2)) * 16 + kg * 4 + (j & 3);
                f[j] = (short)f2bf(Wst[kap * 64 + mt2 * 16 + cl]);
            }
            F.a2[mt2][ks] = f;
        }
        bf16x8 f3 = {};
        if (cl < 3) {
            #pragma unroll
            for (int j = 0; j < 8; ++j) {
                int kap = (2 * ks + (j >> 2)) * 16 + kg * 4 + (j & 3);
                f3[j] = (short)f2bf(Wst[4480 + kap * 3 + cl]);
            }
        }
        F.a3[ks] = f3;
    }
    #pragma unroll
    for (int mt2 = 0; mt2 < 4; ++mt2) {
        f32x4 b;
        #pragma unroll
        for (int r = 0; r < 4; ++r) b[r] = Wst[4672 + mt2 * 16 + kg * 4 + r];
        F.bias2[mt2] = b;
    }
    {
        f32x4 b = {};
        if (kg == 0) { b[0] = Wst[4736]; b[1] = Wst[4737]; b[2] = Wst[4738]; }
        F.bias3 = b;
    }
    __syncthreads();
}

// ---------- pass 0: fp32 emb -> row-paired bf16 table (16 MB) ----------
// tabd[y*1024+x] = {bf16x4 emb[y][x], bf16x4 emb[min(y+1,1023)][x]}
__global__ __launch_bounds__(256) void conv_dup(const f32x4* __restrict__ emb,
                                                u32x4* __restrict__ tabd) {
    int t = blockIdx.x * 256 + threadIdx.x;   // 4096 x 256 == 1M exactly
    int y = t >> 10;
    int y1 = (y + 1 > 1023) ? 1023 : y + 1;
    int xx = t & 1023;
    f32x4 a = emb[(y << 10) + xx];
    f32x4 b = emb[(y1 << 10) + xx];
    u32x4 p = {cvt_pk_bf16(a[0], a[1]), cvt_pk_bf16(a[2], a[3]),
               cvt_pk_bf16(b[0], b[1]), cvt_pk_bf16(b[2], b[3])};
    tabd[t] = p;
}

// ------------------------------ fused kernel --------------------------------
template<int BT>   // 1: row-paired bf16 table; 0: fp32 emb direct
__global__ __launch_bounds__(256, 3)
void dgn_fused(const float* __restrict__ x, const void* __restrict__ tabv,
               const float* __restrict__ w1, const float* __restrict__ b1,
               const float* __restrict__ w2, const float* __restrict__ b2,
               const float* __restrict__ w3, const float* __restrict__ b3,
               float* __restrict__ out, int n)
{
    __shared__ __align__(16) float Wst[4768];   // 19 KB; reused as Xf after build

    const int tid = threadIdx.x, wid = tid >> 6, lane = tid & 63;
    const int cl = lane & 15, kg = lane >> 4;

    TFrags F;
    build_tfrags(Wst, tid, cl, kg, w1, b1, w2, b2, w3, b3, F);

    u32x4* Xf = (u32x4*)Wst + wid * 64;   // per-wave 1 KB transpose buffer

    const u32x4* __restrict__ tabd = (const u32x4*)tabv;
    const f32x4* __restrict__ tabf = (const f32x4*)tabv;

    const int SP   = gridDim.x * 256;
    const int blk0 = blockIdx.x * 256;
    if (blk0 >= n) return;
    const int iters = (n - blk0 + SP - 1) / SP;
    const int wb0   = blk0 + wid * 64;

    #define LOADX(I, A, B, C) { int pt_ = wb0 + (I) * SP + lane;                \
        int pc_ = pt_ < n ? pt_ : 0; const float* xp_ = x + 3 * pc_;            \
        A = xp_[0]; B = xp_[1]; C = xp_[2]; }

    #define GISSUE(U, V, T0, T1, Fv, WX, WY) {                                  \
        float uf_ = (U) * 1024.f, vf_ = (V) * 1024.f;                           \
        int x0_ = (int)uf_; if (x0_ == 1024) x0_ = 0;                           \
        int x1_ = (x0_ + 1 == 1024) ? 1023 : x0_ + 1;                           \
        int y0_ = (int)vf_;                                                     \
        WX = uf_ - (float)x0_; WY = vf_ - (float)y0_;                           \
        if (y0_ > 1023) y0_ = 1023;                                             \
        int r0_ = y0_ << 10;                                                    \
        if (BT) { T0 = tabd[r0_ + x0_]; T1 = tabd[r0_ + x1_]; }                 \
        else {                                                                  \
            int y1_ = (y0_ + 1 > 1023) ? 1023 : y0_ + 1;                        \
            int r1_ = y1_ << 10;                                                \
            Fv[0] = tabf[r0_ + x0_]; Fv[1] = tabf[r0_ + x1_];                   \
            Fv[2] = tabf[r1_ + x0_]; Fv[3] = tabf[r1_ + x1_]; } }

    // -------- depth-2 pipeline prologue --------
    u32x4 cT0 = {}, cT1 = {};
    f32x4 cF[4] = {};
    float cwx, cwy, cid;
    float nx0, nx1, nx2;
    {
        float p0, p1, p2;
        LOADX(0, p0, p1, p2);
        GISSUE(p1, p2, cT0, cT1, cF, cwx, cwy);
        cid = p0;
        LOADX(1, nx0, nx1, nx2);
    }

    for (int i = 0; i < iters; ++i) {
        // issue next tile's 2 texel loads + x(i+2) before this tile's MLP
        u32x4 tT0 = {}, tT1 = {};
        f32x4 tF[4] = {};
        float twx = 0.f, twy = 0.f, tcid = 0.f;
        const bool more = (i + 1 < iters);
        if (more) {
            GISSUE(nx1, nx2, tT0, tT1, tF, twx, twy);
            tcid = nx0;
            int nix = (i + 2 < iters) ? i + 2 : i + 1;
            LOADX(nix, nx0, nx1, nx2);
        }

        // -------- current tile: lerp + pack + lane-transpose via LDS --------
        f32x4 A, B, C, D;   // v00, v10, v01, v11
        if (BT) {
            A = unpk2(cT0[0], cT0[1]);  C = unpk2(cT0[2], cT0[3]);
            B = unpk2(cT1[0], cT1[1]);  D = unpk2(cT1[2], cT1[3]);
        } else { A = cF[0]; B = cF[1]; C = cF[2]; D = cF[3]; }
        f32x4 up = A + (B - A) * cwx;
        f32x4 dn = C + (D - C) * cwx;
        f32x4 g  = up + (dn - up) * cwy;

        u32x4 inq = {cvt_pk_bf16(cid, g[0]), cvt_pk_bf16(g[1], g[2]),
                     cvt_pk_bf16(g[3], 1.0f), 0u};   // slot5 = 1.0 (bias row)
        Xf[lane] = inq;
        lds_fence();
        // B-frags for L1 (kg>=1 rows killed by zero A cols; broadcast reads)
        u32x4 bq0 = Xf[0 * 16 + cl];
        u32x4 bq1 = Xf[1 * 16 + cl];
        u32x4 bq2 = Xf[2 * 16 + cl];
        u32x4 bq3 = Xf[3 * 16 + cl];

        // -------- MLP: per point-tile nt, fully in registers --------
        const int tb = wb0 + i * SP;
        #pragma unroll
        for (int nt = 0; nt < 4; ++nt) {
            u32x4 bqs = (nt == 0) ? bq0 : (nt == 1) ? bq1 : (nt == 2) ? bq2 : bq3;
            bf16x8 bb = __builtin_bit_cast(bf16x8, bqs);

            // L1: C1^T[hid][pt]; acc init 0 (b1 rides k=5)
            f32x4 c1_0 = {}, c1_1 = {}, c1_2 = {}, c1_3 = {};
            c1_0 = MFMA16(F.a1[0], bb, c1_0);
            c1_1 = MFMA16(F.a1[1], bb, c1_1);
            c1_2 = MFMA16(F.a1[2], bb, c1_2);
            c1_3 = MFMA16(F.a1[3], bb, c1_3);

            bf16x8 p0 = pack_pair(c1_0, c1_1);
            bf16x8 p1 = pack_pair(c1_2, c1_3);

            // L2: K=64 (2 k-steps), bias via acc init
            f32x4 c2_0 = F.bias2[0], c2_1 = F.bias2[1],
                  c2_2 = F.bias2[2], c2_3 = F.bias2[3];
            c2_0 = MFMA16(F.a2[0][0], p0, c2_0); c2_0 = MFMA16(F.a2[0][1], p1, c2_0);
            c2_1 = MFMA16(F.a2[1][0], p0, c2_1); c2_1 = MFMA16(F.a2[1][1], p1, c2_1);
            c2_2 = MFMA16(F.a2[2][0], p0, c2_2); c2_2 = MFMA16(F.a2[2][1], p1, c2_2);
            c2_3 = MFMA16(F.a2[3][0], p0, c2_3); c2_3 = MFMA16(F.a2[3][1], p1, c2_3);

            bf16x8 q0 = pack_pair(c2_0, c2_1);
            bf16x8 q1 = pack_pair(c2_2, c2_3);

            // L3: 3 output channels, bias via acc init
            f32x4 c3 = F.bias3;
            c3 = MFMA16(F.a3[0], q0, c3);
            c3 = MFMA16(F.a3[1], q1, c3);

            // sigmoid + store: kg==0 lane cl owns point tb+nt*16+cl, ch=r
            if (kg == 0) {
                int pt = tb + nt * 16 + cl;
                if (pt < n) {
                    #pragma unroll
                    for (int r = 0; r < 3; ++r) {
                        float s = __builtin_amdgcn_rcpf(1.0f + __expf(-c3[r]));
                        out[pt * 3 + r] = s;
                    }
                }
            }
        }

        if (more) {
            cT0 = tT0; cT1 = tT1;
            #pragma unroll
            for (int j = 0; j < 4; ++j) cF[j] = tF[j];
            cwx = twx; cwy = twy; cid = tcid;
        }
    }
    #undef LOADX
    #undef GISSUE
}

extern "C" void kernel_launch(void* const* d_in, const int* in_sizes, int n_in,
                              void* d_out, int out_size, void* d_ws, size_t ws_size,
                              hipStream_t stream) {
    const float* x   = (const float*)d_in[0];
    const float* emb = (const float*)d_in[1];
    const float* w1  = (const float*)d_in[2];
    const float* b1  = (const float*)d_in[3];
    const float* w2  = (const float*)d_in[4];
    const float* b2  = (const float*)d_in[5];
    const float* w3  = (const float*)d_in[6];
    const float* b3  = (const float*)d_in[7];
    float* out = (float*)d_out;

    int n = in_sizes[0] / 3;
    int nblk = (n + 255) / 256;
    if (nblk > 1536) nblk = 1536;   // 6 blocks/CU at runtime (VGPR/LDS both fit)

    const size_t tab_bytes = (size_t)16 * 1024 * 1024;
    if (ws_size >= tab_bytes) {
        conv_dup<<<dim3(4096), dim3(256), 0, stream>>>((const f32x4*)emb, (u32x4*)d_ws);
        dgn_fused<1><<<dim3(nblk), dim3(256), 0, stream>>>(
            x, d_ws, w1, b1, w2, b2, w3, b3, out, n);
    } else {
        dgn_fused<0><<<dim3(nblk), dim3(256), 0, stream>>>(
            x, emb, w1, b1, w2, b2, w3, b3, out, n);
    }
}

// Round 19
// 61.443 us; speedup vs baseline: 1.1151x; 1.1151x over previous
//
#include <hip/hip_runtime.h>
#include <hip/hip_bf16.h>

// DenseGridNet R19 (= R17/R18 with compile fixes): R13 structure (fused gather
// + transposed in-register MFMA MLP, row-paired 16B table, depth-2 pipeline,
// grid 768, launch_bounds(256,3)), datapath in f16:
//  - f16 row-paired table; lerp in packed _Float16 vectors (v_pk_fma_f16)
//  - input K-order [idf, 1.0, g0..g3]: pack = 1 cvt_pkrtz (g words are free)
//  - relu via __builtin_elementwise_max on _Float16 vectors (v_pk_max_f16)
//  - mfma_f32_16x16x32_f16 (same fragment geometry / kappa as bf16 version)
// cvt_pkrtz returns __fp16x2 — always bit_cast, never assign (R17/R18 errors).

typedef _Float16 f16x8 __attribute__((ext_vector_type(8)));
typedef _Float16 h2v   __attribute__((ext_vector_type(2)));
typedef __attribute__((ext_vector_type(4))) float f32x4;
typedef __attribute__((ext_vector_type(4))) unsigned int u32x4;

#define HID 64
#define MFMA16H(a,b,c) __builtin_amdgcn_mfma_f32_16x16x32_f16((a),(b),(c),0,0,0)

static __device__ __forceinline__ void lds_fence() {
    asm volatile("s_waitcnt lgkmcnt(0)" ::: "memory");
}
static __device__ __forceinline__ unsigned pkrtz_u(float a, float b) {
    return __builtin_bit_cast(unsigned, __builtin_amdgcn_cvt_pkrtz(a, b));
}
static __device__ __forceinline__ h2v u2h(unsigned u) {
    return __builtin_bit_cast(h2v, u);
}
static __device__ __forceinline__ unsigned h2u(h2v h) {
    return __builtin_bit_cast(unsigned, h);
}
// cvt f32 pair -> f16 pair, then packed relu (v_pk_max_f16)
static __device__ __forceinline__ unsigned cvtmax(float a, float b) {
    h2v c = __builtin_bit_cast(h2v, __builtin_amdgcn_cvt_pkrtz(a, b));
    h2v z = {(_Float16)0.0f, (_Float16)0.0f};
    c = __builtin_elementwise_max(c, z);
    return __builtin_bit_cast(unsigned, c);
}
static __device__ __forceinline__ f16x8 pack_pair_h(f32x4 lo, f32x4 hi) {
    u32x4 w;
    w[0] = cvtmax(lo[0], lo[1]);
    w[1] = cvtmax(lo[2], lo[3]);
    w[2] = cvtmax(hi[0], hi[1]);
    w[3] = cvtmax(hi[2], hi[3]);
    return __builtin_bit_cast(f16x8, w);
}

// ---- weight A-fragments for the transposed scheme (f16) ----
struct TFrags {
    f16x8 a1[4];         // W1^T rows mt*16+cl; k-order [w1r0, b1, w1r1..r4, 0,0]
    f16x8 a2[4][2];      // W2^T, K in kappa order
    f16x8 a3[2];         // W3^T (rows 0..2 valid), kappa order
    f32x4 bias2[4];
    f32x4 bias3;
};

// Wst layout (floats): [0..4095]=w2, [4096..4415]=w1, [4416..4479]=b1,
//                      [4480..4671]=w3, [4672..4735]=b2, [4736..4738]=b3
static __device__ __forceinline__ void build_tfrags(
    float* Wst, int tid, int cl, int kg,
    const float* __restrict__ w1, const float* __restrict__ b1,
    const float* __restrict__ w2, const float* __restrict__ b2,
    const float* __restrict__ w3, const float* __restrict__ b3, TFrags& F)
{
    {
        const f32x4* w2v = (const f32x4*)w2;
        f32x4* Wv = (f32x4*)Wst;
        #pragma unroll
        for (int i = 0; i < 4; ++i) Wv[tid + 256 * i] = w2v[tid + 256 * i];
        for (int idx = tid; idx < 320; idx += 256) Wst[4096 + idx] = w1[idx];
        if (tid < 64)  Wst[4416 + tid] = b1[tid];
        if (tid < 192) Wst[4480 + tid] = w3[tid];
        if (tid < 64)  Wst[4672 + tid] = b2[tid];
        if (tid < 3)   Wst[4736 + tid] = b3[tid];
    }
    __syncthreads();

    #pragma unroll
    for (int mt = 0; mt < 4; ++mt) {
        f16x8 f = {};
        if (kg == 0) {
            int hid = mt * 16 + cl;
            f[0] = (_Float16)Wst[4096 + 0 * 64 + hid];   // idf row
            f[1] = (_Float16)Wst[4416 + hid];            // bias (input k1 = 1.0)
            f[2] = (_Float16)Wst[4096 + 1 * 64 + hid];   // g0 row
            f[3] = (_Float16)Wst[4096 + 2 * 64 + hid];
            f[4] = (_Float16)Wst[4096 + 3 * 64 + hid];
            f[5] = (_Float16)Wst[4096 + 4 * 64 + hid];
        }
        F.a1[mt] = f;
    }
    #pragma unroll
    for (int ks = 0; ks < 2; ++ks) {
        #pragma unroll
        for (int mt2 = 0; mt2 < 4; ++mt2) {
            f16x8 f;
            #pragma unroll
            for (int j = 0; j < 8; ++j) {
                int kap = (2 * ks + (j >> 2)) * 16 + kg * 4 + (j & 3);
                f[j] = (_Float16)Wst[kap * 64 + mt2 * 16 + cl];
            }
            F.a2[mt2][ks] = f;
        }
        f16x8 f3 = {};
        if (cl < 3) {
            #pragma unroll
            for (int j = 0; j < 8; ++j) {
                int kap = (2 * ks + (j >> 2)) * 16 + kg * 4 + (j & 3);
                f3[j] = (_Float16)Wst[4480 + kap * 3 + cl];
            }
        }
        F.a3[ks] = f3;
    }
    #pragma unroll
    for (int mt2 = 0; mt2 < 4; ++mt2) {
        f32x4 b;
        #pragma unroll
        for (int r = 0; r < 4; ++r) b[r] = Wst[4672 + mt2 * 16 + kg * 4 + r];
        F.bias2[mt2] = b;
    }
    {
        f32x4 b = {};
        if (kg == 0) { b[0] = Wst[4736]; b[1] = Wst[4737]; b[2] = Wst[4738]; }
        F.bias3 = b;
    }
    __syncthreads();
}

// ---------- pass 0: fp32 emb -> row-paired f16 table (16 MB) ----------
// tabd[y*1024+x] = {f16x4 emb[y][x], f16x4 emb[min(y+1,1023)][x]}
__global__ __launch_bounds__(256) void conv_dup(const f32x4* __restrict__ emb,
                                                u32x4* __restrict__ tabd) {
    int t = blockIdx.x * 256 + threadIdx.x;   // 4096 x 256 == 1M exactly
    int y = t >> 10;
    int y1 = (y + 1 > 1023) ? 1023 : y + 1;
    int xx = t & 1023;
    f32x4 a = emb[(y << 10) + xx];
    f32x4 b = emb[(y1 << 10) + xx];
    u32x4 p = {pkrtz_u(a[0], a[1]), pkrtz_u(a[2], a[3]),
               pkrtz_u(b[0], b[1]), pkrtz_u(b[2], b[3])};
    tabd[t] = p;
}

// ------------------------------ fused kernel --------------------------------
template<int BT>   // 1: row-paired f16 table; 0: fp32 emb direct
__global__ __launch_bounds__(256, 3)
void dgn_fused(const float* __restrict__ x, const void* __restrict__ tabv,
               const float* __restrict__ w1, const float* __restrict__ b1,
               const float* __restrict__ w2, const float* __restrict__ b2,
               const float* __restrict__ w3, const float* __restrict__ b3,
               float* __restrict__ out, int n)
{
    __shared__ __align__(16) float Wst[4768];   // 19 KB; reused as Xf after build

    const int tid = threadIdx.x, wid = tid >> 6, lane = tid & 63;
    const int cl = lane & 15, kg = lane >> 4;

    TFrags F;
    build_tfrags(Wst, tid, cl, kg, w1, b1, w2, b2, w3, b3, F);

    u32x4* Xf = (u32x4*)Wst + wid * 64;   // per-wave 1 KB transpose buffer

    const u32x4* __restrict__ tabd = (const u32x4*)tabv;
    const f32x4* __restrict__ tabf = (const f32x4*)tabv;

    const int SP   = gridDim.x * 256;
    const int blk0 = blockIdx.x * 256;
    if (blk0 >= n) return;
    const int iters = (n - blk0 + SP - 1) / SP;
    const int wb0   = blk0 + wid * 64;

    #define LOADX(I, A, B, C) { int pt_ = wb0 + (I) * SP + lane;                \
        int pc_ = pt_ < n ? pt_ : 0; const float* xp_ = x + 3 * pc_;            \
        A = xp_[0]; B = xp_[1]; C = xp_[2]; }

    #define GISSUE(U, V, T0, T1, Fv, WX, WY) {                                  \
        float uf_ = (U) * 1024.f, vf_ = (V) * 1024.f;                           \
        int x0_ = (int)uf_; if (x0_ == 1024) x0_ = 0;                           \
        int x1_ = (x0_ + 1 == 1024) ? 1023 : x0_ + 1;                           \
        int y0_ = (int)vf_;                                                     \
        WX = uf_ - (float)x0_; WY = vf_ - (float)y0_;                           \
        if (y0_ > 1023) y0_ = 1023;                                             \
        int r0_ = y0_ << 10;                                                    \
        if (BT) { T0 = tabd[r0_ + x0_]; T1 = tabd[r0_ + x1_]; }                 \
        else {                                                                  \
            int y1_ = (y0_ + 1 > 1023) ? 1023 : y0_ + 1;                        \
            int r1_ = y1_ << 10;                                                \
            Fv[0] = tabf[r0_ + x0_]; Fv[1] = tabf[r0_ + x1_];                   \
            Fv[2] = tabf[r1_ + x0_]; Fv[3] = tabf[r1_ + x1_]; } }

    // -------- depth-2 pipeline prologue --------
    u32x4 cT0 = {}, cT1 = {};
    f32x4 cF[4] = {};
    float cwx, cwy, cid;
    float nx0, nx1, nx2;
    {
        float p0, p1, p2;
        LOADX(0, p0, p1, p2);
        GISSUE(p1, p2, cT0, cT1, cF, cwx, cwy);
        cid = p0;
        LOADX(1, nx0, nx1, nx2);
    }

    for (int i = 0; i < iters; ++i) {
        // issue next tile's 2 texel loads + x(i+2) before this tile's MLP
        u32x4 tT0 = {}, tT1 = {};
        f32x4 tF[4] = {};
        float twx = 0.f, twy = 0.f, tcid = 0.f;
        const bool more = (i + 1 < iters);
        if (more) {
            GISSUE(nx1, nx2, tT0, tT1, tF, twx, twy);
            tcid = nx0;
            int nix = (i + 2 < iters) ? i + 2 : i + 1;
            LOADX(nix, nx0, nx1, nx2);
        }

        // -------- current tile: packed-f16 lerp + pack + LDS transpose --------
        u32x4 inq;
        if (BT) {
            _Float16 wxh = (_Float16)cwx, wyh = (_Float16)cwy;
            h2v wx2 = {wxh, wxh};
            h2v wy2 = {wyh, wyh};
            h2v A01 = u2h(cT0[0]), A23 = u2h(cT0[1]);
            h2v C01 = u2h(cT0[2]), C23 = u2h(cT0[3]);
            h2v B01 = u2h(cT1[0]), B23 = u2h(cT1[1]);
            h2v D01 = u2h(cT1[2]), D23 = u2h(cT1[3]);
            h2v up01 = (B01 - A01) * wx2 + A01;
            h2v up23 = (B23 - A23) * wx2 + A23;
            h2v dn01 = (D01 - C01) * wx2 + C01;
            h2v dn23 = (D23 - C23) * wx2 + C23;
            h2v g01  = (dn01 - up01) * wy2 + up01;
            h2v g23  = (dn23 - up23) * wy2 + up23;
            inq = (u32x4){pkrtz_u(cid, 1.0f), h2u(g01), h2u(g23), 0u};
        } else {
            f32x4 A = cF[0], B = cF[1], C = cF[2], D = cF[3];
            f32x4 up = A + (B - A) * cwx;
            f32x4 dn = C + (D - C) * cwx;
            f32x4 g  = up + (dn - up) * cwy;
            inq = (u32x4){pkrtz_u(cid, 1.0f), pkrtz_u(g[0], g[1]),
                          pkrtz_u(g[2], g[3]), 0u};
        }
        Xf[lane] = inq;
        lds_fence();
        // B-frags for L1 (kg>=1 lanes' K-slices killed by zero A elements)
        u32x4 bq0 = Xf[0 * 16 + cl];
        u32x4 bq1 = Xf[1 * 16 + cl];
        u32x4 bq2 = Xf[2 * 16 + cl];
        u32x4 bq3 = Xf[3 * 16 + cl];

        // -------- MLP: per point-tile nt, fully in registers --------
        const int tb = wb0 + i * SP;
        #pragma unroll
        for (int nt = 0; nt < 4; ++nt) {
            u32x4 bqs = (nt == 0) ? bq0 : (nt == 1) ? bq1 : (nt == 2) ? bq2 : bq3;
            f16x8 bb = __builtin_bit_cast(f16x8, bqs);

            // L1: C1^T[hid][pt]; acc init 0 (b1 rides k=1, input k1 = 1.0)
            f32x4 c1_0 = {}, c1_1 = {}, c1_2 = {}, c1_3 = {};
            c1_0 = MFMA16H(F.a1[0], bb, c1_0);
            c1_1 = MFMA16H(F.a1[1], bb, c1_1);
            c1_2 = MFMA16H(F.a1[2], bb, c1_2);
            c1_3 = MFMA16H(F.a1[3], bb, c1_3);

            f16x8 p0 = pack_pair_h(c1_0, c1_1);
            f16x8 p1 = pack_pair_h(c1_2, c1_3);

            // L2: K=64 (2 k-steps), bias via acc init
            f32x4 c2_0 = F.bias2[0], c2_1 = F.bias2[1],
                  c2_2 = F.bias2[2], c2_3 = F.bias2[3];
            c2_0 = MFMA16H(F.a2[0][0], p0, c2_0); c2_0 = MFMA16H(F.a2[0][1], p1, c2_0);
            c2_1 = MFMA16H(F.a2[1][0], p0, c2_1); c2_1 = MFMA16H(F.a2[1][1], p1, c2_1);
            c2_2 = MFMA16H(F.a2[2][0], p0, c2_2); c2_2 = MFMA16H(F.a2[2][1], p1, c2_2);
            c2_3 = MFMA16H(F.a2[3][0], p0, c2_3); c2_3 = MFMA16H(F.a2[3][1], p1, c2_3);

            f16x8 q0 = pack_pair_h(c2_0, c2_1);
            f16x8 q1 = pack_pair_h(c2_2, c2_3);

            // L3: 3 output channels, bias via acc init
            f32x4 c3 = F.bias3;
            c3 = MFMA16H(F.a3[0], q0, c3);
            c3 = MFMA16H(F.a3[1], q1, c3);

            // sigmoid + store: kg==0 lane cl owns point tb+nt*16+cl, ch=r
            if (kg == 0) {
                int pt = tb + nt * 16 + cl;
                if (pt < n) {
                    #pragma unroll
                    for (int r = 0; r < 3; ++r) {
                        float s = __builtin_amdgcn_rcpf(1.0f + __expf(-c3[r]));
                        out[pt * 3 + r] = s;
                    }
                }
            }
        }

        if (more) {
            cT0 = tT0; cT1 = tT1;
            #pragma unroll
            for (int j = 0; j < 4; ++j) cF[j] = tF[j];
            cwx = twx; cwy = twy; cid = tcid;
        }
    }
    #undef LOADX
    #undef GISSUE
}

extern "C" void kernel_launch(void* const* d_in, const int* in_sizes, int n_in,
                              void* d_out, int out_size, void* d_ws, size_t ws_size,
                              hipStream_t stream) {
    const float* x   = (const float*)d_in[0];
    const float* emb = (const float*)d_in[1];
    const float* w1  = (const float*)d_in[2];
    const float* b1  = (const float*)d_in[3];
    const float* w2  = (const float*)d_in[4];
    const float* b2  = (const float*)d_in[5];
    const float* w3  = (const float*)d_in[6];
    const float* b3  = (const float*)d_in[7];
    float* out = (float*)d_out;

    int n = in_sizes[0] / 3;
    int nblk = (n + 255) / 256;
    if (nblk > 768) nblk = 768;   // R13's measured-best geometry

    const size_t tab_bytes = (size_t)16 * 1024 * 1024;
    if (ws_size >= tab_bytes) {
        conv_dup<<<dim3(4096), dim3(256), 0, stream>>>((const f32x4*)emb, (u32x4*)d_ws);
        dgn_fused<1><<<dim3(nblk), dim3(256), 0, stream>>>(
            x, d_ws, w1, b1, w2, b2, w3, b3, out, n);
    } else {
        dgn_fused<0><<<dim3(nblk), dim3(256), 0, stream>>>(
            x, emb, w1, b1, w2, b2, w3, b3, out, n);
    }
}